// Round 2
// baseline (221.172 us; speedup 1.0000x reference)
//
#include <hip/hip_runtime.h>
#include <hip/hip_bf16.h>

// Gaussians: quaternions (N,4) f32 + scales (N,3) f32 -> covariance (N,3,3) f32.
// C = (R*diag(s)) (R*diag(s))^T  (symmetric: 6 unique entries).
// Memory-bound: 256 MB total traffic, ~41 us pure-traffic floor at 6.3 TB/s.
// R5: overlay the scale-staging buffer onto the cov-staging buffer (live ranges
// disjoint up to a register copy). LDS 24 KB -> 18 KB: 6 -> 8 blocks/CU
// (24 -> 32 waves/CU, max occupancy) for better latency hiding on the
// BW-bound streams. Costs one extra __syncthreads() (WAR: other waves' scale
// reads vs my cov writes); compute is placed BEFORE that barrier so the
// barrier2->barrier3 window contains only the ds_writes.

#define BLK 256
#define PPT 2
#define PPB (BLK * PPT)        // 512 points per block
#define SFLOATS (PPB * 3)      // 1536 scale floats per block
#define SVEC4   (SFLOATS / 4)  // 384 float4 loads per block

typedef float vfloat4 __attribute__((ext_vector_type(4)));

__device__ __forceinline__ void compute_cov(vfloat4 q, float sx, float sy, float sz,
                                            float* c /*6: 00,01,02,11,12,22*/)
{
    float r = q.x, x = q.y, y = q.z, z = q.w;
    float nrm = sqrtf(r*r + x*x + y*y + z*z);
    nrm = fmaxf(nrm, 1e-12f);
    float inv = 1.0f / nrm;
    r *= inv; x *= inv; y *= inv; z *= inv;

    float R00 = 1.0f - 2.0f*(y*y + z*z);
    float R01 = 2.0f*(x*y - r*z);
    float R02 = 2.0f*(x*z + r*y);
    float R10 = 2.0f*(x*y + r*z);
    float R11 = 1.0f - 2.0f*(x*x + z*z);
    float R12 = 2.0f*(y*z - r*x);
    float R20 = 2.0f*(x*z - r*y);
    float R21 = 2.0f*(y*z + r*x);
    float R22 = 1.0f - 2.0f*(x*x + y*y);

    float sx2 = sx*sx, sy2 = sy*sy, sz2 = sz*sz;

    c[0] = R00*R00*sx2 + R01*R01*sy2 + R02*R02*sz2; // 00
    c[1] = R00*R10*sx2 + R01*R11*sy2 + R02*R12*sz2; // 01
    c[2] = R00*R20*sx2 + R01*R21*sy2 + R02*R22*sz2; // 02
    c[3] = R10*R10*sx2 + R11*R11*sy2 + R12*R12*sz2; // 11
    c[4] = R10*R20*sx2 + R11*R21*sy2 + R12*R22*sz2; // 12
    c[5] = R20*R20*sx2 + R21*R21*sy2 + R22*R22*sz2; // 22
}

__global__ __launch_bounds__(BLK) void gaussians_cov_kernel(
    const vfloat4* __restrict__ quat,   // N x 4 viewed as float4
    const float*   __restrict__ scales, // N x 3 floats
    float*         __restrict__ out,    // N x 9 floats
    int n)
{
    // Single 18 KB buffer: floats [0, SFLOATS) double as the scale stage
    // before the covariance results are written.
    __shared__ float s_buf[PPB * 9];

    const int t = threadIdx.x;
    const long long base = (long long)blockIdx.x * PPB;

    if (base + PPB <= n) {
        // ---- fast path ----
        // Stage scales: 384 coalesced float4 nt loads (single-touch stream).
        // scales + 3*base is 16B-aligned: 12*base bytes, base % 4 == 0.
        {
            const vfloat4* sg = (const vfloat4*)(scales + 3 * base);
            vfloat4* sl = (vfloat4*)s_buf;
            sl[t] = __builtin_nontemporal_load(&sg[t]);
            if (t < SVEC4 - BLK)   // t < 128
                sl[BLK + t] = __builtin_nontemporal_load(&sg[BLK + t]);
        }

        vfloat4 q0 = __builtin_nontemporal_load(&quat[base + t]);
        vfloat4 q1 = __builtin_nontemporal_load(&quat[base + BLK + t]);

        __syncthreads();   // barrier 1: scale stage visible

        // Stride-3 LDS reads: odd stride -> 2-way bank aliasing, free.
        const float* sp0 = s_buf + 3 * t;
        const float* sp1 = s_buf + 3 * (BLK + t);
        float s0x = sp0[0], s0y = sp0[1], s0z = sp0[2];
        float s1x = sp1[0], s1y = sp1[1], s1z = sp1[2];

        // Full compute BEFORE barrier 2 -> waves arrive having done the work.
        float c0[6], c1[6];
        compute_cov(q0, s0x, s0y, s0z, c0);
        compute_cov(q1, s1x, s1y, s1z, c1);

        __syncthreads();   // barrier 2: WAR — all scale reads done before reuse

        // stride-9 LDS writes: odd stride -> 2-way bank aliasing, free
        float* cp0 = s_buf + 9 * t;
        cp0[0] = c0[0]; cp0[1] = c0[1]; cp0[2] = c0[2];
        cp0[3] = c0[1]; cp0[4] = c0[3]; cp0[5] = c0[4];
        cp0[6] = c0[2]; cp0[7] = c0[4]; cp0[8] = c0[5];
        float* cp1 = s_buf + 9 * (BLK + t);
        cp1[0] = c1[0]; cp1[1] = c1[1]; cp1[2] = c1[2];
        cp1[3] = c1[1]; cp1[4] = c1[3]; cp1[5] = c1[4];
        cp1[6] = c1[2]; cp1[7] = c1[4]; cp1[8] = c1[5];

        __syncthreads();   // barrier 3: cov stage visible

        // blast 4608 floats = 1152 float4 contiguous, nt coalesced stores
        const vfloat4* src = (const vfloat4*)s_buf;
        vfloat4* dst = (vfloat4*)(out + base * 9);
        #pragma unroll
        for (int k = 0; k < 5; ++k) {
            int idx = k * BLK + t;
            if (idx < (PPB * 9) / 4)
                __builtin_nontemporal_store(src[idx], &dst[idx]);
        }
    } else {
        // ---- tail path (last partial block) ----
        for (int p = 0; p < PPT; ++p) {
            long long i = base + p * BLK + t;
            if (i < n) {
                vfloat4 q = quat[i];
                const float* sp = scales + 3 * i;
                float c[6];
                compute_cov(q, sp[0], sp[1], sp[2], c);
                float* op = out + 9 * i;
                op[0] = c[0]; op[1] = c[1]; op[2] = c[2];
                op[3] = c[1]; op[4] = c[3]; op[5] = c[4];
                op[6] = c[2]; op[7] = c[4]; op[8] = c[5];
            }
        }
    }
}

extern "C" void kernel_launch(void* const* d_in, const int* in_sizes, int n_in,
                              void* d_out, int out_size, void* d_ws, size_t ws_size,
                              hipStream_t stream)
{
    const vfloat4* quat   = (const vfloat4*)d_in[0];
    const float*   scales = (const float*)d_in[1];
    float*         out    = (float*)d_out;
    int n = in_sizes[0] / 4;   // quaternions is N x 4

    int grid = (n + PPB - 1) / PPB;
    gaussians_cov_kernel<<<grid, BLK, 0, stream>>>(quat, scales, out, n);
}

// Round 3
// 217.313 us; speedup vs baseline: 1.0178x; 1.0178x over previous
//
#include <hip/hip_runtime.h>
#include <hip/hip_bf16.h>

// Gaussians: quaternions (N,4) f32 + scales (N,3) f32 -> covariance (N,3,3) f32.
// C = (R*diag(s)) (R*diag(s))^T  (symmetric: 6 unique entries).
// Memory-bound: 256 MB total traffic, ~41 us pure-traffic floor at 6.3 TB/s.
// R6 = revert to R4 (best measured: 217.7 us). R5's LDS overlay (18 KB,
// 8 blocks/CU) + third barrier REGRESSED to 221.2: occupancy was not the
// limiter at 24 waves/CU, and the extra barrier's vmcnt(0) drain re-exposed
// memory latency once more per block. Keep: scales staged through LDS as
// coalesced float4 nt loads (1.5/thread), quat as float4 nt loads, output
// staged in a separate LDS buffer and blasted as contiguous float4 nt stores.
// LDS 24 KB -> 6 blocks/CU = 24 waves/CU, two barriers total.

#define BLK 256
#define PPT 2
#define PPB (BLK * PPT)        // 512 points per block
#define SFLOATS (PPB * 3)      // 1536 scale floats per block
#define SVEC4   (SFLOATS / 4)  // 384 float4 loads per block

typedef float vfloat4 __attribute__((ext_vector_type(4)));

__device__ __forceinline__ void compute_cov(vfloat4 q, float sx, float sy, float sz,
                                            float* c /*6: 00,01,02,11,12,22*/)
{
    float r = q.x, x = q.y, y = q.z, z = q.w;
    float nrm = sqrtf(r*r + x*x + y*y + z*z);
    nrm = fmaxf(nrm, 1e-12f);
    float inv = 1.0f / nrm;
    r *= inv; x *= inv; y *= inv; z *= inv;

    float R00 = 1.0f - 2.0f*(y*y + z*z);
    float R01 = 2.0f*(x*y - r*z);
    float R02 = 2.0f*(x*z + r*y);
    float R10 = 2.0f*(x*y + r*z);
    float R11 = 1.0f - 2.0f*(x*x + z*z);
    float R12 = 2.0f*(y*z - r*x);
    float R20 = 2.0f*(x*z - r*y);
    float R21 = 2.0f*(y*z + r*x);
    float R22 = 1.0f - 2.0f*(x*x + y*y);

    float sx2 = sx*sx, sy2 = sy*sy, sz2 = sz*sz;

    c[0] = R00*R00*sx2 + R01*R01*sy2 + R02*R02*sz2; // 00
    c[1] = R00*R10*sx2 + R01*R11*sy2 + R02*R12*sz2; // 01
    c[2] = R00*R20*sx2 + R01*R21*sy2 + R02*R22*sz2; // 02
    c[3] = R10*R10*sx2 + R11*R11*sy2 + R12*R12*sz2; // 11
    c[4] = R10*R20*sx2 + R11*R21*sy2 + R12*R22*sz2; // 12
    c[5] = R20*R20*sx2 + R21*R21*sy2 + R22*R22*sz2; // 22
}

__global__ __launch_bounds__(BLK) void gaussians_cov_kernel(
    const vfloat4* __restrict__ quat,   // N x 4 viewed as float4
    const float*   __restrict__ scales, // N x 3 floats
    float*         __restrict__ out,    // N x 9 floats
    int n)
{
    __shared__ float s_scl[SFLOATS];    // 6 KB  (staged scales)
    __shared__ float s_cov[PPB * 9];    // 18 KB (staged output)

    const int t = threadIdx.x;
    const long long base = (long long)blockIdx.x * PPB;

    if (base + PPB <= n) {
        // ---- fast path ----
        // Stage scales: 384 coalesced float4 nt loads (single-touch stream).
        // scales + 3*base is 16B-aligned: 12*base bytes, base % 4 == 0.
        {
            const vfloat4* sg = (const vfloat4*)(scales + 3 * base);
            vfloat4* sl = (vfloat4*)s_scl;
            sl[t] = __builtin_nontemporal_load(&sg[t]);
            if (t < SVEC4 - BLK)   // t < 128
                sl[BLK + t] = __builtin_nontemporal_load(&sg[BLK + t]);
        }

        vfloat4 q0 = __builtin_nontemporal_load(&quat[base + t]);
        vfloat4 q1 = __builtin_nontemporal_load(&quat[base + BLK + t]);

        __syncthreads();   // barrier 1: scale stage visible

        // Stride-3 LDS reads: odd stride -> 2-way bank aliasing, free.
        const float* sp0 = s_scl + 3 * t;
        const float* sp1 = s_scl + 3 * (BLK + t);
        float s0x = sp0[0], s0y = sp0[1], s0z = sp0[2];
        float s1x = sp1[0], s1y = sp1[1], s1z = sp1[2];

        float c0[6], c1[6];
        compute_cov(q0, s0x, s0y, s0z, c0);
        compute_cov(q1, s1x, s1y, s1z, c1);

        // stride-9 LDS writes: odd stride -> 2-way bank aliasing, free
        float* cp0 = s_cov + 9 * t;
        cp0[0] = c0[0]; cp0[1] = c0[1]; cp0[2] = c0[2];
        cp0[3] = c0[1]; cp0[4] = c0[3]; cp0[5] = c0[4];
        cp0[6] = c0[2]; cp0[7] = c0[4]; cp0[8] = c0[5];
        float* cp1 = s_cov + 9 * (BLK + t);
        cp1[0] = c1[0]; cp1[1] = c1[1]; cp1[2] = c1[2];
        cp1[3] = c1[1]; cp1[4] = c1[3]; cp1[5] = c1[4];
        cp1[6] = c1[2]; cp1[7] = c1[4]; cp1[8] = c1[5];
        __syncthreads();   // barrier 2: cov stage visible

        // blast 4608 floats = 1152 float4 contiguous, nt coalesced stores
        const vfloat4* src = (const vfloat4*)s_cov;
        vfloat4* dst = (vfloat4*)(out + base * 9);
        #pragma unroll
        for (int k = 0; k < 5; ++k) {
            int idx = k * BLK + t;
            if (idx < (PPB * 9) / 4)
                __builtin_nontemporal_store(src[idx], &dst[idx]);
        }
    } else {
        // ---- tail path (last partial block) ----
        for (int p = 0; p < PPT; ++p) {
            long long i = base + p * BLK + t;
            if (i < n) {
                vfloat4 q = quat[i];
                const float* sp = scales + 3 * i;
                float c[6];
                compute_cov(q, sp[0], sp[1], sp[2], c);
                float* op = out + 9 * i;
                op[0] = c[0]; op[1] = c[1]; op[2] = c[2];
                op[3] = c[1]; op[4] = c[3]; op[5] = c[4];
                op[6] = c[2]; op[7] = c[4]; op[8] = c[5];
            }
        }
    }
}

extern "C" void kernel_launch(void* const* d_in, const int* in_sizes, int n_in,
                              void* d_out, int out_size, void* d_ws, size_t ws_size,
                              hipStream_t stream)
{
    const vfloat4* quat   = (const vfloat4*)d_in[0];
    const float*   scales = (const float*)d_in[1];
    float*         out    = (float*)d_out;
    int n = in_sizes[0] / 4;   // quaternions is N x 4

    int grid = (n + PPB - 1) / PPB;
    gaussians_cov_kernel<<<grid, BLK, 0, stream>>>(quat, scales, out, n);
}